// Round 4
// baseline (177.404 us; speedup 1.0000x reference)
//
#include <hip/hip_runtime.h>
#include <hip/hip_bf16.h>

#define BN_EPS 1e-5f

typedef __attribute__((ext_vector_type(8))) short bf16x8;
typedef __attribute__((ext_vector_type(4))) float f32x4;

__device__ __forceinline__ unsigned short f2bf(float f) {
    union { float f; unsigned u; } x; x.f = f;
    unsigned u = x.u;
    unsigned r = (u + 0x7fffu + ((u >> 16) & 1u)) >> 16;  // RTNE
    return (unsigned short)r;
}

// ---------------- f32 -> bf16 pre-conversion for x and W in one launch ----------------
__global__ __launch_bounds__(256) void cvt_bf16_kernel(
    const float* __restrict__ x, unsigned short* __restrict__ xb, int nx8,
    const float* __restrict__ W, unsigned short* __restrict__ Wb, int nw8)
{
    int i = blockIdx.x * 256 + threadIdx.x;
    const float* in; unsigned short* out; int idx;
    if (i < nx8) { in = x; out = xb; idx = i; }
    else if (i < nx8 + nw8) { in = W; out = Wb; idx = i - nx8; }
    else return;
    const float4* p = reinterpret_cast<const float4*>(in) + (size_t)idx * 2;
    float4 lo = p[0], hi = p[1];
    union { unsigned short us[8]; uint4 v; } pk;
    pk.us[0] = f2bf(lo.x); pk.us[1] = f2bf(lo.y); pk.us[2] = f2bf(lo.z); pk.us[3] = f2bf(lo.w);
    pk.us[4] = f2bf(hi.x); pk.us[5] = f2bf(hi.y); pk.us[6] = f2bf(hi.z); pk.us[7] = f2bf(hi.w);
    reinterpret_cast<uint4*>(out)[idx] = pk.v;
}

// ---------------- 256x256-tile GEMM + ghostBN + prior-scale ----------------
// 8 waves (2M x 4N), BK=64, double-buffered LDS (128 KB), counted-vmcnt pipeline:
// raw s_barrier + vmcnt(8) (never drained to 0 in the main loop).
// Per-wave output = 128 rows x 64 cols; 128 rows == one virtual batch, so the
// GhostBN reduction is entirely wave-local (shfl only, no LDS, no barrier).
__global__ __launch_bounds__(512, 2) void gemm_bn_256_kernel(
    const unsigned short* __restrict__ xb,  // [B, K] bf16
    const unsigned short* __restrict__ Wb,  // [F, K] bf16
    const float* __restrict__ gamma,
    const float* __restrict__ beta,
    const float* __restrict__ prior,
    float* __restrict__ z,
    int B, int F, int K)
{
    const int tid  = threadIdx.x;
    const int lane = tid & 63;
    const int wid  = tid >> 6;   // 0..7
    const int wr   = wid >> 2;   // 0..1  M-half
    const int wn   = wid & 3;    // 0..3  N-quarter
    const int row0 = blockIdx.y * 256;
    const int col0 = blockIdx.x * 256;
    const int l15  = lane & 15;
    const int lq   = lane >> 4;

    __shared__ __align__(16) unsigned short As[2][256 * 64];  // 2 x 32 KB
    __shared__ __align__(16) unsigned short Bs[2][256 * 64];  // 2 x 32 KB

    f32x4 acc[8][4];
    const f32x4 zero = {0.f, 0.f, 0.f, 0.f};
#pragma unroll
    for (int m = 0; m < 8; ++m)
#pragma unroll
        for (int n = 0; n < 4; ++n) acc[m][n] = zero;

    // staging: 2048 16B-chunks per matrix per K-tile; 4 per thread.
    // chunk c -> row = c>>3, lin slot = c&7; source slot pre-swizzled (rule #21)
    // so the linear LDS write lands XOR-swizzled for conflict-free frag reads.
    auto STAGE = [&](int buf, int k0) {
#pragma unroll
        for (int j = 0; j < 4; ++j) {
            int c = (wid * 4 + j) * 64 + lane;
            int row = c >> 3;
            int s_src = (c & 7) ^ (row & 7);
            unsigned ldsoff = (unsigned)(wid * 4 + j) * 1024;  // bytes, wave-uniform
            const unsigned short* ga = xb + (size_t)(row0 + row) * K + k0 + s_src * 8;
            __builtin_amdgcn_global_load_lds(
                (const __attribute__((address_space(1))) void*)ga,
                (__attribute__((address_space(3))) void*)((char*)As[buf] + ldsoff), 16, 0, 0);
            const unsigned short* gb = Wb + (size_t)(col0 + row) * K + k0 + s_src * 8;
            __builtin_amdgcn_global_load_lds(
                (const __attribute__((address_space(1))) void*)gb,
                (__attribute__((address_space(3))) void*)((char*)Bs[buf] + ldsoff), 16, 0, 0);
        }
    };

    const int NT = K >> 6;  // 8

    // Prologue: stage tiles 0 and 1; wait only for tile 0 (8 newest stay in flight).
    STAGE(0, 0);
    STAGE(1, 64);
    asm volatile("s_waitcnt vmcnt(8)" ::: "memory");
    __builtin_amdgcn_sched_barrier(0);
    __builtin_amdgcn_s_barrier();

    for (int t = 0; t < NT; ++t) {
        const int b = t & 1;
        bf16x8 af[8], bf[4];

        // ---- ks = 0: read frags, MFMA ----
#pragma unroll
        for (int m = 0; m < 8; ++m) {
            int r = wr * 128 + m * 16 + l15;
            af[m] = *reinterpret_cast<const bf16x8*>(&As[b][r * 64 + ((lq ^ (r & 7)) * 8)]);
        }
#pragma unroll
        for (int n = 0; n < 4; ++n) {
            int r = wn * 64 + n * 16 + l15;
            bf[n] = *reinterpret_cast<const bf16x8*>(&Bs[b][r * 64 + ((lq ^ (r & 7)) * 8)]);
        }
        asm volatile("s_waitcnt lgkmcnt(0)" ::: "memory");
        __builtin_amdgcn_sched_barrier(0);
#pragma unroll
        for (int m = 0; m < 8; ++m)
#pragma unroll
            for (int n = 0; n < 4; ++n)
                acc[m][n] = __builtin_amdgcn_mfma_f32_16x16x32_bf16(af[m], bf[n], acc[m][n], 0, 0, 0);

        // ---- ks = 1: read frags (this completes ALL reads of buf b) ----
#pragma unroll
        for (int m = 0; m < 8; ++m) {
            int r = wr * 128 + m * 16 + l15;
            int s = 4 + lq;
            af[m] = *reinterpret_cast<const bf16x8*>(&As[b][r * 64 + ((s ^ (r & 7)) * 8)]);
        }
#pragma unroll
        for (int n = 0; n < 4; ++n) {
            int r = wn * 64 + n * 16 + l15;
            int s = 4 + lq;
            bf[n] = *reinterpret_cast<const bf16x8*>(&Bs[b][r * 64 + ((s ^ (r & 7)) * 8)]);
        }
        asm volatile("s_waitcnt lgkmcnt(0)" ::: "memory");
        __builtin_amdgcn_sched_barrier(0);
        __builtin_amdgcn_s_barrier();           // all waves finished reading buf b

        // ---- stage tile t+2 into the now-dead buf b, overlapped with ks1 MFMA ----
        if (t + 2 < NT) STAGE(b, (t + 2) << 6);
        __builtin_amdgcn_sched_barrier(0);
        __builtin_amdgcn_s_setprio(1);
#pragma unroll
        for (int m = 0; m < 8; ++m)
#pragma unroll
            for (int n = 0; n < 4; ++n)
                acc[m][n] = __builtin_amdgcn_mfma_f32_16x16x32_bf16(af[m], bf[n], acc[m][n], 0, 0, 0);
        __builtin_amdgcn_s_setprio(0);
        __builtin_amdgcn_sched_barrier(0);

        // ---- counted wait: tile t+1 landed (t+2's 8 loads may stay in flight) ----
        if (t + 2 < NT) asm volatile("s_waitcnt vmcnt(8)" ::: "memory");
        else            asm volatile("s_waitcnt vmcnt(0)" ::: "memory");
        __builtin_amdgcn_sched_barrier(0);
        __builtin_amdgcn_s_barrier();
    }

    // ---- GhostBN: wave-local per-column stats over this wave's 128 rows ----
#pragma unroll
    for (int n = 0; n < 4; ++n) {
        float s = 0.f, q = 0.f;
#pragma unroll
        for (int m = 0; m < 8; ++m)
#pragma unroll
            for (int r = 0; r < 4; ++r) { float v = acc[m][n][r]; s += v; q += v * v; }
        s += __shfl_xor(s, 16); q += __shfl_xor(q, 16);
        s += __shfl_xor(s, 32); q += __shfl_xor(q, 32);
        float mu  = s * (1.f / 128.f);
        float var = q * (1.f / 128.f) - mu * mu;
        float rv  = rsqrtf(var + BN_EPS);
        int cg = col0 + wn * 64 + n * 16 + l15;
        float g  = gamma[cg] * rv;
        float bt = beta[cg] - mu * g;
#pragma unroll
        for (int m = 0; m < 8; ++m) {
#pragma unroll
            for (int r = 0; r < 4; ++r) {
                int rg = row0 + wr * 128 + m * 16 + lq * 4 + r;
                size_t idx = (size_t)rg * F + cg;
                z[idx] = (acc[m][n][r] * g + bt) * prior[idx];
            }
        }
    }
}

// ---------------- fallback (f32 inputs, in-loop convert) ----------------
__global__ __launch_bounds__(256, 2) void gemm_bn_kernel(
    const float* __restrict__ x, const float* __restrict__ W,
    const float* __restrict__ gamma, const float* __restrict__ beta,
    const float* __restrict__ prior, float* __restrict__ z,
    int B, int F, int K)
{
    const int tid  = threadIdx.x;
    const int lane = tid & 63;
    const int wid  = tid >> 6;
    const int wr   = wid >> 1;
    const int wc   = wid & 1;
    const int row0 = blockIdx.y * 128;
    const int col0 = blockIdx.x * 128;
    const int l15  = lane & 15;
    const int lq   = lane >> 4;

    __shared__ __align__(16) unsigned short As[128 * 64];
    __shared__ __align__(16) unsigned short Bs[128 * 64];
    __shared__ float red[2][128][2];

    f32x4 acc[4][4];
    const f32x4 zero = {0.f, 0.f, 0.f, 0.f};
#pragma unroll
    for (int m = 0; m < 4; ++m)
#pragma unroll
        for (int n = 0; n < 4; ++n) acc[m][n] = zero;

    for (int k0 = 0; k0 < K; k0 += 64) {
#pragma unroll
        for (int i = 0; i < 4; ++i) {
            int c = tid + i * 256;
            int r = c >> 3;
            int s = c & 7;
            {
                const float4* pa = reinterpret_cast<const float4*>(x + (size_t)(row0 + r) * K + k0 + s * 8);
                float4 lo = pa[0], hi = pa[1];
                union { unsigned short us[8]; uint4 v; } pk;
                pk.us[0] = f2bf(lo.x); pk.us[1] = f2bf(lo.y); pk.us[2] = f2bf(lo.z); pk.us[3] = f2bf(lo.w);
                pk.us[4] = f2bf(hi.x); pk.us[5] = f2bf(hi.y); pk.us[6] = f2bf(hi.z); pk.us[7] = f2bf(hi.w);
                *reinterpret_cast<uint4*>(&As[r * 64 + ((s ^ (r & 7)) * 8)]) = pk.v;
            }
            {
                const float4* pb = reinterpret_cast<const float4*>(W + (size_t)(col0 + r) * K + k0 + s * 8);
                float4 lo = pb[0], hi = pb[1];
                union { unsigned short us[8]; uint4 v; } pk;
                pk.us[0] = f2bf(lo.x); pk.us[1] = f2bf(lo.y); pk.us[2] = f2bf(lo.z); pk.us[3] = f2bf(lo.w);
                pk.us[4] = f2bf(hi.x); pk.us[5] = f2bf(hi.y); pk.us[6] = f2bf(hi.z); pk.us[7] = f2bf(hi.w);
                *reinterpret_cast<uint4*>(&Bs[r * 64 + ((s ^ (r & 7)) * 8)]) = pk.v;
            }
        }
        __syncthreads();
#pragma unroll
        for (int ks = 0; ks < 2; ++ks) {
            bf16x8 af[4], bfr[4];
#pragma unroll
            for (int m = 0; m < 4; ++m) {
                int r = wr * 64 + m * 16 + l15;
                int s = ks * 4 + lq;
                af[m] = *reinterpret_cast<const bf16x8*>(&As[r * 64 + ((s ^ (r & 7)) * 8)]);
            }
#pragma unroll
            for (int n = 0; n < 4; ++n) {
                int r = wc * 64 + n * 16 + l15;
                int s = ks * 4 + lq;
                bfr[n] = *reinterpret_cast<const bf16x8*>(&Bs[r * 64 + ((s ^ (r & 7)) * 8)]);
            }
#pragma unroll
            for (int m = 0; m < 4; ++m)
#pragma unroll
                for (int n = 0; n < 4; ++n)
                    acc[m][n] = __builtin_amdgcn_mfma_f32_16x16x32_bf16(af[m], bfr[n], acc[m][n], 0, 0, 0);
        }
        __syncthreads();
    }

    float psum[4], psq[4];
#pragma unroll
    for (int n = 0; n < 4; ++n) {
        float s = 0.f, q = 0.f;
#pragma unroll
        for (int m = 0; m < 4; ++m)
#pragma unroll
            for (int r = 0; r < 4; ++r) { float v = acc[m][n][r]; s += v; q += v * v; }
        s += __shfl_xor(s, 16); q += __shfl_xor(q, 16);
        s += __shfl_xor(s, 32); q += __shfl_xor(q, 32);
        psum[n] = s; psq[n] = q;
    }
    if (lane < 16) {
#pragma unroll
        for (int n = 0; n < 4; ++n) {
            red[wr][wc * 64 + n * 16 + lane][0] = psum[n];
            red[wr][wc * 64 + n * 16 + lane][1] = psq[n];
        }
    }
    __syncthreads();

#pragma unroll
    for (int n = 0; n < 4; ++n) {
        int cl = wc * 64 + n * 16 + l15;
        int cg = col0 + cl;
        float tot = red[0][cl][0] + red[1][cl][0];
        float tsq = red[0][cl][1] + red[1][cl][1];
        float mu  = tot * (1.f / 128.f);
        float var = tsq * (1.f / 128.f) - mu * mu;
        float rv  = rsqrtf(var + BN_EPS);
        float g   = gamma[cg] * rv;
        float bt  = beta[cg] - mu * g;
#pragma unroll
        for (int m = 0; m < 4; ++m) {
#pragma unroll
            for (int r = 0; r < 4; ++r) {
                int rg = row0 + wr * 64 + m * 16 + lq * 4 + r;
                size_t idx = (size_t)rg * F + cg;
                z[idx] = (acc[m][n][r] * g + bt) * prior[idx];
            }
        }
    }
}

// ---------------- sparsemax (Michelot fixed-point), one wave per row ----------------
__global__ __launch_bounds__(256, 4) void sparsemax_kernel(float* __restrict__ z, int B, int F)
{
    const int lane = threadIdx.x & 63;
    const int wid  = threadIdx.x >> 6;
    const int row  = blockIdx.x * 4 + wid;
    if (row >= B) return;
    float* rp = z + (size_t)row * F;

    float4 v[8];
    float s = 0.f;
#pragma unroll
    for (int j = 0; j < 8; ++j) {
        v[j] = reinterpret_cast<const float4*>(rp)[j * 64 + lane];
        s += v[j].x + v[j].y + v[j].z + v[j].w;
    }
#pragma unroll
    for (int o = 32; o; o >>= 1) s += __shfl_xor(s, o);

    float tau = (s - 1.f) / (float)F;
    int cprev = F;
    for (int it = 0; it < 64; ++it) {
        float s2 = 0.f; int c2 = 0;
#pragma unroll
        for (int j = 0; j < 8; ++j) {
            if (v[j].x > tau) { s2 += v[j].x; ++c2; }
            if (v[j].y > tau) { s2 += v[j].y; ++c2; }
            if (v[j].z > tau) { s2 += v[j].z; ++c2; }
            if (v[j].w > tau) { s2 += v[j].w; ++c2; }
        }
#pragma unroll
        for (int o = 32; o; o >>= 1) { s2 += __shfl_xor(s2, o); c2 += __shfl_xor(c2, o); }
        if (c2 == cprev) break;
        tau = (s2 - 1.f) / (float)c2;
        cprev = c2;
    }

#pragma unroll
    for (int j = 0; j < 8; ++j) {
        float4 o4;
        o4.x = fmaxf(v[j].x - tau, 0.f);
        o4.y = fmaxf(v[j].y - tau, 0.f);
        o4.z = fmaxf(v[j].z - tau, 0.f);
        o4.w = fmaxf(v[j].w - tau, 0.f);
        reinterpret_cast<float4*>(rp)[j * 64 + lane] = o4;
    }
}

extern "C" void kernel_launch(void* const* d_in, const int* in_sizes, int n_in,
                              void* d_out, int out_size, void* d_ws, size_t ws_size,
                              hipStream_t stream) {
    const float* x     = (const float*)d_in[0];
    const float* prior = (const float*)d_in[1];
    const float* W     = (const float*)d_in[2];
    const float* gamma = (const float*)d_in[3];
    const float* beta  = (const float*)d_in[4];
    float* out = (float*)d_out;

    const int F = in_sizes[3];              // 2048
    const int K = in_sizes[2] / F;          // 512
    const int B = in_sizes[0] / K;          // 16384

    const size_t nx = (size_t)B * K;
    const size_t nw = (size_t)F * K;
    const size_t need = (nx + nw) * sizeof(unsigned short);

    if (ws_size >= need) {
        unsigned short* xb = (unsigned short*)d_ws;
        unsigned short* Wb = xb + nx;
        int nx8 = (int)(nx / 8), nw8 = (int)(nw / 8);
        int tot8 = nx8 + nw8;
        cvt_bf16_kernel<<<dim3((tot8 + 255) / 256), dim3(256), 0, stream>>>(x, xb, nx8, W, Wb, nw8);
        dim3 g1(F / 256, B / 256);          // (8, 64) = 512 blocks, 1/CU resident
        gemm_bn_256_kernel<<<g1, dim3(512), 0, stream>>>(xb, Wb, gamma, beta, prior, out, B, F, K);
    } else {
        dim3 g1(F / 128, B / 128);
        gemm_bn_kernel<<<g1, dim3(256), 0, stream>>>(x, W, gamma, beta, prior, out, B, F, K);
    }
    sparsemax_kernel<<<dim3(B / 4), dim3(256), 0, stream>>>(out, B, F);
}

// Round 5
// 166.836 us; speedup vs baseline: 1.0633x; 1.0633x over previous
//
#include <hip/hip_runtime.h>
#include <hip/hip_bf16.h>

#define BN_EPS 1e-5f

typedef __attribute__((ext_vector_type(8))) short bf16x8;
typedef __attribute__((ext_vector_type(4))) float f32x4;

__device__ __forceinline__ unsigned short f2bf(float f) {
    union { float f; unsigned u; } x; x.f = f;
    unsigned u = x.u;
    unsigned r = (u + 0x7fffu + ((u >> 16) & 1u)) >> 16;  // RTNE
    return (unsigned short)r;
}

// ---------------- f32 -> bf16 pre-conversion for x and W in one launch ----------------
__global__ __launch_bounds__(256) void cvt_bf16_kernel(
    const float* __restrict__ x, unsigned short* __restrict__ xb, int nx8,
    const float* __restrict__ W, unsigned short* __restrict__ Wb, int nw8)
{
    int i = blockIdx.x * 256 + threadIdx.x;
    const float* in; unsigned short* out; int idx;
    if (i < nx8) { in = x; out = xb; idx = i; }
    else if (i < nx8 + nw8) { in = W; out = Wb; idx = i - nx8; }
    else return;
    const float4* p = reinterpret_cast<const float4*>(in) + (size_t)idx * 2;
    float4 lo = p[0], hi = p[1];
    union { unsigned short us[8]; uint4 v; } pk;
    pk.us[0] = f2bf(lo.x); pk.us[1] = f2bf(lo.y); pk.us[2] = f2bf(lo.z); pk.us[3] = f2bf(lo.w);
    pk.us[4] = f2bf(hi.x); pk.us[5] = f2bf(hi.y); pk.us[6] = f2bf(hi.z); pk.us[7] = f2bf(hi.w);
    reinterpret_cast<uint4*>(out)[idx] = pk.v;
}

// ---------------- 128x128-tile GEMM + ghostBN + prior-scale ----------------
// 4 waves, each owning 128 rows x 32 cols (-> GhostBN wave-local, no epilogue sync).
// A staged in double-buffered LDS via global_load_lds (src-side XOR swizzle, rule #21);
// B (W, 2 MB, L2-resident) loaded directly global->reg each K-step.
// Pipeline: per-iter B-loads are issued AFTER the staged prefetch of tile t+1, so the
// compiler's exact vmcnt waits for B also retire the older staging loads -> no manual
// vmcnt in the loop, no vmcnt(0) drain; 2 raw s_barriers per K-step.
__global__ __launch_bounds__(256, 3) void gemm_bn_bdir_kernel(
    const unsigned short* __restrict__ xb,  // [B, K] bf16
    const unsigned short* __restrict__ Wb,  // [F, K] bf16
    const float* __restrict__ gamma,
    const float* __restrict__ beta,
    const float* __restrict__ prior,
    float* __restrict__ z,
    int B, int F, int K)
{
    const int tid  = threadIdx.x;
    const int lane = tid & 63;
    const int wid  = tid >> 6;   // 0..3: column strip [wid*32, wid*32+32)
    const int l15  = lane & 15;
    const int lq   = lane >> 4;

    // XCD-chunked swizzle (T1): nwg divisible by 8; bx-inner so the 16 col-blocks
    // sharing one x row-panel co-run on the same XCD (x-panel + W fit 4 MB L2).
    const int nwg = gridDim.x;
    const int cpx = nwg >> 3;
    const int id  = blockIdx.x;
    const int sw  = (id & 7) * cpx + (id >> 3);
    const int nbx = F >> 7;
    const int bx  = sw % nbx;
    const int by  = sw / nbx;
    const int row0 = by * 128;
    const int col0 = bx * 128;

    __shared__ __align__(16) unsigned short As[2][128 * 64];  // 2 x 16 KB

    f32x4 acc[8][2];
    const f32x4 zero = {0.f, 0.f, 0.f, 0.f};
#pragma unroll
    for (int m = 0; m < 8; ++m) { acc[m][0] = zero; acc[m][1] = zero; }

    // staging: 1024 16B chunks, 4/thread; linear LDS dest, pre-swizzled global src.
    auto STAGE = [&](int buf, int k0) {
#pragma unroll
        for (int j = 0; j < 4; ++j) {
            int c = (wid * 4 + j) * 64 + lane;
            int row = c >> 3;
            int s_src = (c & 7) ^ (row & 7);
            unsigned ldsoff = (unsigned)(wid * 4 + j) * 1024;  // wave-uniform bytes
            const unsigned short* g = xb + (size_t)(row0 + row) * K + k0 + s_src * 8;
            __builtin_amdgcn_global_load_lds(
                (const __attribute__((address_space(1))) void*)g,
                (__attribute__((address_space(3))) void*)((char*)As[buf] + ldsoff), 16, 0, 0);
        }
    };

    // per-lane W base pointers for the two 16-col fragments of this wave's strip
    const unsigned short* wbase0 = Wb + (size_t)(col0 + wid * 32 + l15) * K + lq * 8;
    const unsigned short* wbase1 = wbase0 + (size_t)16 * K;

    const int NT = K >> 6;  // 8

    STAGE(0, 0);
    STAGE(1, 64);
    asm volatile("s_waitcnt vmcnt(4)" ::: "memory");   // tile 0 landed; tile 1 in flight
    __builtin_amdgcn_sched_barrier(0);
    __builtin_amdgcn_s_barrier();
    __builtin_amdgcn_sched_barrier(0);

    for (int t = 0; t < NT; ++t) {
        const int b  = t & 1;
        const int k0 = t << 6;

        // B fragments for both K=32 halves, straight from L2-resident W.
        bf16x8 b00 = *reinterpret_cast<const bf16x8*>(wbase0 + k0);
        bf16x8 b01 = *reinterpret_cast<const bf16x8*>(wbase1 + k0);
        bf16x8 b10 = *reinterpret_cast<const bf16x8*>(wbase0 + k0 + 32);
        bf16x8 b11 = *reinterpret_cast<const bf16x8*>(wbase1 + k0 + 32);

        bf16x8 af[8];
        // ---- ks = 0 ----
#pragma unroll
        for (int m = 0; m < 8; ++m) {
            int r = m * 16 + l15;
            af[m] = *reinterpret_cast<const bf16x8*>(&As[b][r * 64 + ((lq ^ (r & 7)) * 8)]);
        }
        asm volatile("s_waitcnt lgkmcnt(0)" ::: "memory");
        __builtin_amdgcn_sched_barrier(0);
        __builtin_amdgcn_s_setprio(1);
#pragma unroll
        for (int m = 0; m < 8; ++m) {
            acc[m][0] = __builtin_amdgcn_mfma_f32_16x16x32_bf16(af[m], b00, acc[m][0], 0, 0, 0);
            acc[m][1] = __builtin_amdgcn_mfma_f32_16x16x32_bf16(af[m], b01, acc[m][1], 0, 0, 0);
        }
        __builtin_amdgcn_s_setprio(0);

        // ---- ks = 1 reads (completes all reads of buf b) ----
#pragma unroll
        for (int m = 0; m < 8; ++m) {
            int r = m * 16 + l15;
            int s = 4 + lq;
            af[m] = *reinterpret_cast<const bf16x8*>(&As[b][r * 64 + ((s ^ (r & 7)) * 8)]);
        }
        asm volatile("s_waitcnt lgkmcnt(0)" ::: "memory");
        __builtin_amdgcn_sched_barrier(0);
        __builtin_amdgcn_s_barrier();                 // B1: all waves done reading buf b
        __builtin_amdgcn_sched_barrier(0);

        if (t + 2 < NT) STAGE(b, (t + 2) << 6);       // prefetch into the dead buffer

        __builtin_amdgcn_s_setprio(1);
#pragma unroll
        for (int m = 0; m < 8; ++m) {
            acc[m][0] = __builtin_amdgcn_mfma_f32_16x16x32_bf16(af[m], b10, acc[m][0], 0, 0, 0);
            acc[m][1] = __builtin_amdgcn_mfma_f32_16x16x32_bf16(af[m], b11, acc[m][1], 0, 0, 0);
        }
        __builtin_amdgcn_s_setprio(0);
        __builtin_amdgcn_sched_barrier(0);
        __builtin_amdgcn_s_barrier();                 // B2: every wave passed its B-wait,
        __builtin_amdgcn_sched_barrier(0);            //     so stage(t+1) is fully visible
    }

    // ---- GhostBN: fully wave-local (wave owns all 128 rows of its columns) ----
#pragma unroll
    for (int n = 0; n < 2; ++n) {
        float s = 0.f, q = 0.f;
#pragma unroll
        for (int m = 0; m < 8; ++m)
#pragma unroll
            for (int r = 0; r < 4; ++r) { float v = acc[m][n][r]; s += v; q += v * v; }
        s += __shfl_xor(s, 16); q += __shfl_xor(q, 16);
        s += __shfl_xor(s, 32); q += __shfl_xor(q, 32);
        float mu  = s * (1.f / 128.f);
        float var = q * (1.f / 128.f) - mu * mu;
        float rv  = rsqrtf(var + BN_EPS);
        int cg = col0 + wid * 32 + n * 16 + l15;
        float g  = gamma[cg] * rv;
        float bt = beta[cg] - mu * g;
#pragma unroll
        for (int m = 0; m < 8; ++m) {
#pragma unroll
            for (int r = 0; r < 4; ++r) {
                int rg = row0 + m * 16 + lq * 4 + r;
                size_t idx = (size_t)rg * F + cg;
                z[idx] = (acc[m][n][r] * g + bt) * prior[idx];
            }
        }
    }
}

// ---------------- fallback (f32 inputs, in-loop convert) ----------------
__global__ __launch_bounds__(256, 2) void gemm_bn_kernel(
    const float* __restrict__ x, const float* __restrict__ W,
    const float* __restrict__ gamma, const float* __restrict__ beta,
    const float* __restrict__ prior, float* __restrict__ z,
    int B, int F, int K)
{
    const int tid  = threadIdx.x;
    const int lane = tid & 63;
    const int wid  = tid >> 6;
    const int wr   = wid >> 1;
    const int wc   = wid & 1;
    const int row0 = blockIdx.y * 128;
    const int col0 = blockIdx.x * 128;
    const int l15  = lane & 15;
    const int lq   = lane >> 4;

    __shared__ __align__(16) unsigned short As[128 * 64];
    __shared__ __align__(16) unsigned short Bs[128 * 64];
    __shared__ float red[2][128][2];

    f32x4 acc[4][4];
    const f32x4 zero = {0.f, 0.f, 0.f, 0.f};
#pragma unroll
    for (int m = 0; m < 4; ++m)
#pragma unroll
        for (int n = 0; n < 4; ++n) acc[m][n] = zero;

    for (int k0 = 0; k0 < K; k0 += 64) {
#pragma unroll
        for (int i = 0; i < 4; ++i) {
            int c = tid + i * 256;
            int r = c >> 3;
            int s = c & 7;
            {
                const float4* pa = reinterpret_cast<const float4*>(x + (size_t)(row0 + r) * K + k0 + s * 8);
                float4 lo = pa[0], hi = pa[1];
                union { unsigned short us[8]; uint4 v; } pk;
                pk.us[0] = f2bf(lo.x); pk.us[1] = f2bf(lo.y); pk.us[2] = f2bf(lo.z); pk.us[3] = f2bf(lo.w);
                pk.us[4] = f2bf(hi.x); pk.us[5] = f2bf(hi.y); pk.us[6] = f2bf(hi.z); pk.us[7] = f2bf(hi.w);
                *reinterpret_cast<uint4*>(&As[r * 64 + ((s ^ (r & 7)) * 8)]) = pk.v;
            }
            {
                const float4* pb = reinterpret_cast<const float4*>(W + (size_t)(col0 + r) * K + k0 + s * 8);
                float4 lo = pb[0], hi = pb[1];
                union { unsigned short us[8]; uint4 v; } pk;
                pk.us[0] = f2bf(lo.x); pk.us[1] = f2bf(lo.y); pk.us[2] = f2bf(lo.z); pk.us[3] = f2bf(lo.w);
                pk.us[4] = f2bf(hi.x); pk.us[5] = f2bf(hi.y); pk.us[6] = f2bf(hi.z); pk.us[7] = f2bf(hi.w);
                *reinterpret_cast<uint4*>(&Bs[r * 64 + ((s ^ (r & 7)) * 8)]) = pk.v;
            }
        }
        __syncthreads();
#pragma unroll
        for (int ks = 0; ks < 2; ++ks) {
            bf16x8 af[4], bfr[4];
#pragma unroll
            for (int m = 0; m < 4; ++m) {
                int r = wr * 64 + m * 16 + l15;
                int s = ks * 4 + lq;
                af[m] = *reinterpret_cast<const bf16x8*>(&As[r * 64 + ((s ^ (r & 7)) * 8)]);
            }
#pragma unroll
            for (int n = 0; n < 4; ++n) {
                int r = wc * 64 + n * 16 + l15;
                int s = ks * 4 + lq;
                bfr[n] = *reinterpret_cast<const bf16x8*>(&Bs[r * 64 + ((s ^ (r & 7)) * 8)]);
            }
#pragma unroll
            for (int m = 0; m < 4; ++m)
#pragma unroll
                for (int n = 0; n < 4; ++n)
                    acc[m][n] = __builtin_amdgcn_mfma_f32_16x16x32_bf16(af[m], bfr[n], acc[m][n], 0, 0, 0);
        }
        __syncthreads();
    }

    float psum[4], psq[4];
#pragma unroll
    for (int n = 0; n < 4; ++n) {
        float s = 0.f, q = 0.f;
#pragma unroll
        for (int m = 0; m < 4; ++m)
#pragma unroll
            for (int r = 0; r < 4; ++r) { float v = acc[m][n][r]; s += v; q += v * v; }
        s += __shfl_xor(s, 16); q += __shfl_xor(q, 16);
        s += __shfl_xor(s, 32); q += __shfl_xor(q, 32);
        psum[n] = s; psq[n] = q;
    }
    if (lane < 16) {
#pragma unroll
        for (int n = 0; n < 4; ++n) {
            red[wr][wc * 64 + n * 16 + lane][0] = psum[n];
            red[wr][wc * 64 + n * 16 + lane][1] = psq[n];
        }
    }
    __syncthreads();

#pragma unroll
    for (int n = 0; n < 4; ++n) {
        int cl = wc * 64 + n * 16 + l15;
        int cg = col0 + cl;
        float tot = red[0][cl][0] + red[1][cl][0];
        float tsq = red[0][cl][1] + red[1][cl][1];
        float mu  = tot * (1.f / 128.f);
        float var = tsq * (1.f / 128.f) - mu * mu;
        float rv  = rsqrtf(var + BN_EPS);
        float g   = gamma[cg] * rv;
        float bt  = beta[cg] - mu * g;
#pragma unroll
        for (int m = 0; m < 4; ++m) {
#pragma unroll
            for (int r = 0; r < 4; ++r) {
                int rg = row0 + wr * 64 + m * 16 + lq * 4 + r;
                size_t idx = (size_t)rg * F + cg;
                z[idx] = (acc[m][n][r] * g + bt) * prior[idx];
            }
        }
    }
}

// ---------------- sparsemax (Michelot fixed-point), one wave per row ----------------
__global__ __launch_bounds__(256, 4) void sparsemax_kernel(float* __restrict__ z, int B, int F)
{
    const int lane = threadIdx.x & 63;
    const int wid  = threadIdx.x >> 6;
    const int row  = blockIdx.x * 4 + wid;
    if (row >= B) return;
    float* rp = z + (size_t)row * F;

    float4 v[8];
    float s = 0.f;
#pragma unroll
    for (int j = 0; j < 8; ++j) {
        v[j] = reinterpret_cast<const float4*>(rp)[j * 64 + lane];
        s += v[j].x + v[j].y + v[j].z + v[j].w;
    }
#pragma unroll
    for (int o = 32; o; o >>= 1) s += __shfl_xor(s, o);

    float tau = (s - 1.f) / (float)F;
    int cprev = F;
    for (int it = 0; it < 64; ++it) {
        float s2 = 0.f; int c2 = 0;
#pragma unroll
        for (int j = 0; j < 8; ++j) {
            if (v[j].x > tau) { s2 += v[j].x; ++c2; }
            if (v[j].y > tau) { s2 += v[j].y; ++c2; }
            if (v[j].z > tau) { s2 += v[j].z; ++c2; }
            if (v[j].w > tau) { s2 += v[j].w; ++c2; }
        }
#pragma unroll
        for (int o = 32; o; o >>= 1) { s2 += __shfl_xor(s2, o); c2 += __shfl_xor(c2, o); }
        if (c2 == cprev) break;
        tau = (s2 - 1.f) / (float)c2;
        cprev = c2;
    }

#pragma unroll
    for (int j = 0; j < 8; ++j) {
        float4 o4;
        o4.x = fmaxf(v[j].x - tau, 0.f);
        o4.y = fmaxf(v[j].y - tau, 0.f);
        o4.z = fmaxf(v[j].z - tau, 0.f);
        o4.w = fmaxf(v[j].w - tau, 0.f);
        reinterpret_cast<float4*>(rp)[j * 64 + lane] = o4;
    }
}

extern "C" void kernel_launch(void* const* d_in, const int* in_sizes, int n_in,
                              void* d_out, int out_size, void* d_ws, size_t ws_size,
                              hipStream_t stream) {
    const float* x     = (const float*)d_in[0];
    const float* prior = (const float*)d_in[1];
    const float* W     = (const float*)d_in[2];
    const float* gamma = (const float*)d_in[3];
    const float* beta  = (const float*)d_in[4];
    float* out = (float*)d_out;

    const int F = in_sizes[3];              // 2048
    const int K = in_sizes[2] / F;          // 512
    const int B = in_sizes[0] / K;          // 16384

    const size_t nx = (size_t)B * K;
    const size_t nw = (size_t)F * K;
    const size_t need = (nx + nw) * sizeof(unsigned short);

    if (ws_size >= need) {
        unsigned short* xb = (unsigned short*)d_ws;
        unsigned short* Wb = xb + nx;
        int nx8 = (int)(nx / 8), nw8 = (int)(nw / 8);
        int tot8 = nx8 + nw8;
        cvt_bf16_kernel<<<dim3((tot8 + 255) / 256), dim3(256), 0, stream>>>(x, xb, nx8, W, Wb, nw8);
        int nwg = (F / 128) * (B / 128);    // 2048, divisible by 8
        gemm_bn_bdir_kernel<<<dim3(nwg), dim3(256), 0, stream>>>(xb, Wb, gamma, beta, prior, out, B, F, K);
    } else {
        dim3 g1(F / 128, B / 128);
        gemm_bn_kernel<<<g1, dim3(256), 0, stream>>>(x, W, gamma, beta, prior, out, B, F, K);
    }
    sparsemax_kernel<<<dim3(B / 4), dim3(256), 0, stream>>>(out, B, F);
}

// Round 6
// 135.825 us; speedup vs baseline: 1.3061x; 1.2283x over previous
//
#include <hip/hip_runtime.h>
#include <hip/hip_bf16.h>

#define BN_EPS 1e-5f

typedef __attribute__((ext_vector_type(8))) short bf16x8;
typedef __attribute__((ext_vector_type(4))) float f32x4;

__device__ __forceinline__ unsigned short f2bf(float f) {
    union { float f; unsigned u; } x; x.f = f;
    unsigned u = x.u;
    unsigned r = (u + 0x7fffu + ((u >> 16) & 1u)) >> 16;  // RTNE
    return (unsigned short)r;
}

// ---------------- f32 -> bf16 pre-conversion for x and W in one launch ----------------
__global__ __launch_bounds__(256) void cvt_bf16_kernel(
    const float* __restrict__ x, unsigned short* __restrict__ xb, int nx8,
    const float* __restrict__ W, unsigned short* __restrict__ Wb, int nw8)
{
    int i = blockIdx.x * 256 + threadIdx.x;
    const float* in; unsigned short* out; int idx;
    if (i < nx8) { in = x; out = xb; idx = i; }
    else if (i < nx8 + nw8) { in = W; out = Wb; idx = i - nx8; }
    else return;
    const float4* p = reinterpret_cast<const float4*>(in) + (size_t)idx * 2;
    float4 lo = p[0], hi = p[1];
    union { unsigned short us[8]; uint4 v; } pk;
    pk.us[0] = f2bf(lo.x); pk.us[1] = f2bf(lo.y); pk.us[2] = f2bf(lo.z); pk.us[3] = f2bf(lo.w);
    pk.us[4] = f2bf(hi.x); pk.us[5] = f2bf(hi.y); pk.us[6] = f2bf(hi.z); pk.us[7] = f2bf(hi.w);
    reinterpret_cast<uint4*>(out)[idx] = pk.v;
}

// ---------------- main GEMM + ghostBN + prior-scale (round-2 structure + prior prefetch) ----------------
// 128x128 tile, BK=64, dbuf LDS, global_load_lds width=16, source-side XOR swizzle.
// NEW (T14): the block's prior tile (64 scalars/thread) is loaded into registers at
// K-loop start, so prior's 134 MB (87% of this kernel's fetch bytes, together with the
// z write) streams DURING the K-loop instead of serializing in the epilogue burst.
__global__ __launch_bounds__(256, 2) void gemm_bn_db_kernel(
    const unsigned short* __restrict__ xb,  // [B, K] bf16
    const unsigned short* __restrict__ Wb,  // [F, K] bf16
    const float* __restrict__ gamma,
    const float* __restrict__ beta,
    const float* __restrict__ prior,
    float* __restrict__ z,
    int B, int F, int K)
{
    const int tid  = threadIdx.x;
    const int lane = tid & 63;
    const int wid  = tid >> 6;
    const int wr   = wid >> 1;
    const int wc   = wid & 1;
    const int row0 = blockIdx.y * 128;
    const int col0 = blockIdx.x * 128;
    const int l15  = lane & 15;
    const int lq   = lane >> 4;

    __shared__ __align__(16) unsigned short As[2][128 * 64];  // 2 x 16 KB
    __shared__ __align__(16) unsigned short Bs[2][128 * 64];  // 2 x 16 KB
    __shared__ float red[2][128][2];

    f32x4 acc[4][4];
    const f32x4 zero = {0.f, 0.f, 0.f, 0.f};
#pragma unroll
    for (int m = 0; m < 4; ++m)
#pragma unroll
        for (int n = 0; n < 4; ++n) acc[m][n] = zero;

    const int cbase = wid * 256 + lane;

    auto STAGE = [&](int buf, int k0) {
#pragma unroll
        for (int j = 0; j < 4; ++j) {
            int c = cbase + j * 64;
            int row = c >> 3;
            int s_src = (c & 7) ^ (row & 7);
            unsigned ldsoff = (unsigned)(wid * 4 + j) * 1024;  // bytes, wave-uniform
            {
                const unsigned short* g = xb + (size_t)(row0 + row) * K + k0 + s_src * 8;
                __builtin_amdgcn_global_load_lds(
                    (const __attribute__((address_space(1))) void*)g,
                    (__attribute__((address_space(3))) void*)((char*)As[buf] + ldsoff),
                    16, 0, 0);
            }
            {
                const unsigned short* g = Wb + (size_t)(col0 + row) * K + k0 + s_src * 8;
                __builtin_amdgcn_global_load_lds(
                    (const __attribute__((address_space(1))) void*)g,
                    (__attribute__((address_space(3))) void*)((char*)Bs[buf] + ldsoff),
                    16, 0, 0);
            }
        }
    };

    const int NT = K >> 6;  // 8
    STAGE(0, 0);

    // ---- prior prefetch: issue all 64 loads now; they retire under the K-loop's
    // barriers while other blocks compute. sched_barrier pins the issue point. ----
    float pv[4][4][4];
#pragma unroll
    for (int m = 0; m < 4; ++m)
#pragma unroll
        for (int n = 0; n < 4; ++n) {
            int cg = col0 + wc * 64 + n * 16 + l15;
#pragma unroll
            for (int r = 0; r < 4; ++r) {
                int rg = row0 + wr * 64 + m * 16 + lq * 4 + r;
                pv[m][n][r] = prior[(size_t)rg * F + cg];
            }
        }
    __builtin_amdgcn_sched_barrier(0);

    __syncthreads();

    for (int t = 0; t < NT; ++t) {
        const int cur = t & 1;
        if (t + 1 < NT) STAGE(cur ^ 1, (t + 1) << 6);  // prefetch next tile first

#pragma unroll
        for (int ks = 0; ks < 2; ++ks) {
            bf16x8 af[4], bfr[4];
#pragma unroll
            for (int m = 0; m < 4; ++m) {
                int r = wr * 64 + m * 16 + l15;
                int s = ks * 4 + lq;
                af[m] = *reinterpret_cast<const bf16x8*>(&As[cur][r * 64 + ((s ^ (r & 7)) * 8)]);
            }
#pragma unroll
            for (int n = 0; n < 4; ++n) {
                int r = wc * 64 + n * 16 + l15;
                int s = ks * 4 + lq;
                bfr[n] = *reinterpret_cast<const bf16x8*>(&Bs[cur][r * 64 + ((s ^ (r & 7)) * 8)]);
            }
#pragma unroll
            for (int m = 0; m < 4; ++m)
#pragma unroll
                for (int n = 0; n < 4; ++n)
                    acc[m][n] = __builtin_amdgcn_mfma_f32_16x16x32_bf16(af[m], bfr[n], acc[m][n], 0, 0, 0);
        }
        __syncthreads();
    }

    // ---- GhostBN stats: per-column sum/sumsq over this block's 128 rows ----
    float psum[4], psq[4];
#pragma unroll
    for (int n = 0; n < 4; ++n) {
        float s = 0.f, q = 0.f;
#pragma unroll
        for (int m = 0; m < 4; ++m)
#pragma unroll
            for (int r = 0; r < 4; ++r) { float v = acc[m][n][r]; s += v; q += v * v; }
        s += __shfl_xor(s, 16); q += __shfl_xor(q, 16);
        s += __shfl_xor(s, 32); q += __shfl_xor(q, 32);
        psum[n] = s; psq[n] = q;
    }
    if (lane < 16) {
#pragma unroll
        for (int n = 0; n < 4; ++n) {
            red[wr][wc * 64 + n * 16 + lane][0] = psum[n];
            red[wr][wc * 64 + n * 16 + lane][1] = psq[n];
        }
    }
    __syncthreads();

    // ---- epilogue: BN + prior scale (prior already in regs), stores only ----
#pragma unroll
    for (int n = 0; n < 4; ++n) {
        int cl = wc * 64 + n * 16 + l15;
        int cg = col0 + cl;
        float tot = red[0][cl][0] + red[1][cl][0];
        float tsq = red[0][cl][1] + red[1][cl][1];
        float mu  = tot * (1.f / 128.f);
        float var = tsq * (1.f / 128.f) - mu * mu;
        float rv  = rsqrtf(var + BN_EPS);
        float g   = gamma[cg] * rv;
        float bt  = beta[cg] - mu * g;
#pragma unroll
        for (int m = 0; m < 4; ++m) {
#pragma unroll
            for (int r = 0; r < 4; ++r) {
                int rg = row0 + wr * 64 + m * 16 + lq * 4 + r;
                size_t idx = (size_t)rg * F + cg;
                z[idx] = (acc[m][n][r] * g + bt) * pv[m][n][r];
            }
        }
    }
}

// ---------------- fallback (f32 inputs, in-loop convert) ----------------
__global__ __launch_bounds__(256, 2) void gemm_bn_kernel(
    const float* __restrict__ x, const float* __restrict__ W,
    const float* __restrict__ gamma, const float* __restrict__ beta,
    const float* __restrict__ prior, float* __restrict__ z,
    int B, int F, int K)
{
    const int tid  = threadIdx.x;
    const int lane = tid & 63;
    const int wid  = tid >> 6;
    const int wr   = wid >> 1;
    const int wc   = wid & 1;
    const int row0 = blockIdx.y * 128;
    const int col0 = blockIdx.x * 128;
    const int l15  = lane & 15;
    const int lq   = lane >> 4;

    __shared__ __align__(16) unsigned short As[128 * 64];
    __shared__ __align__(16) unsigned short Bs[128 * 64];
    __shared__ float red[2][128][2];

    f32x4 acc[4][4];
    const f32x4 zero = {0.f, 0.f, 0.f, 0.f};
#pragma unroll
    for (int m = 0; m < 4; ++m)
#pragma unroll
        for (int n = 0; n < 4; ++n) acc[m][n] = zero;

    for (int k0 = 0; k0 < K; k0 += 64) {
#pragma unroll
        for (int i = 0; i < 4; ++i) {
            int c = tid + i * 256;
            int r = c >> 3;
            int s = c & 7;
            {
                const float4* pa = reinterpret_cast<const float4*>(x + (size_t)(row0 + r) * K + k0 + s * 8);
                float4 lo = pa[0], hi = pa[1];
                union { unsigned short us[8]; uint4 v; } pk;
                pk.us[0] = f2bf(lo.x); pk.us[1] = f2bf(lo.y); pk.us[2] = f2bf(lo.z); pk.us[3] = f2bf(lo.w);
                pk.us[4] = f2bf(hi.x); pk.us[5] = f2bf(hi.y); pk.us[6] = f2bf(hi.z); pk.us[7] = f2bf(hi.w);
                *reinterpret_cast<uint4*>(&As[r * 64 + ((s ^ (r & 7)) * 8)]) = pk.v;
            }
            {
                const float4* pb = reinterpret_cast<const float4*>(W + (size_t)(col0 + r) * K + k0 + s * 8);
                float4 lo = pb[0], hi = pb[1];
                union { unsigned short us[8]; uint4 v; } pk;
                pk.us[0] = f2bf(lo.x); pk.us[1] = f2bf(lo.y); pk.us[2] = f2bf(lo.z); pk.us[3] = f2bf(lo.w);
                pk.us[4] = f2bf(hi.x); pk.us[5] = f2bf(hi.y); pk.us[6] = f2bf(hi.z); pk.us[7] = f2bf(hi.w);
                *reinterpret_cast<uint4*>(&Bs[r * 64 + ((s ^ (r & 7)) * 8)]) = pk.v;
            }
        }
        __syncthreads();
#pragma unroll
        for (int ks = 0; ks < 2; ++ks) {
            bf16x8 af[4], bfr[4];
#pragma unroll
            for (int m = 0; m < 4; ++m) {
                int r = wr * 64 + m * 16 + l15;
                int s = ks * 4 + lq;
                af[m] = *reinterpret_cast<const bf16x8*>(&As[r * 64 + ((s ^ (r & 7)) * 8)]);
            }
#pragma unroll
            for (int n = 0; n < 4; ++n) {
                int r = wc * 64 + n * 16 + l15;
                int s = ks * 4 + lq;
                bfr[n] = *reinterpret_cast<const bf16x8*>(&Bs[r * 64 + ((s ^ (r & 7)) * 8)]);
            }
#pragma unroll
            for (int m = 0; m < 4; ++m)
#pragma unroll
                for (int n = 0; n < 4; ++n)
                    acc[m][n] = __builtin_amdgcn_mfma_f32_16x16x32_bf16(af[m], bfr[n], acc[m][n], 0, 0, 0);
        }
        __syncthreads();
    }

    float psum[4], psq[4];
#pragma unroll
    for (int n = 0; n < 4; ++n) {
        float s = 0.f, q = 0.f;
#pragma unroll
        for (int m = 0; m < 4; ++m)
#pragma unroll
            for (int r = 0; r < 4; ++r) { float v = acc[m][n][r]; s += v; q += v * v; }
        s += __shfl_xor(s, 16); q += __shfl_xor(q, 16);
        s += __shfl_xor(s, 32); q += __shfl_xor(q, 32);
        psum[n] = s; psq[n] = q;
    }
    if (lane < 16) {
#pragma unroll
        for (int n = 0; n < 4; ++n) {
            red[wr][wc * 64 + n * 16 + lane][0] = psum[n];
            red[wr][wc * 64 + n * 16 + lane][1] = psq[n];
        }
    }
    __syncthreads();

#pragma unroll
    for (int n = 0; n < 4; ++n) {
        int cl = wc * 64 + n * 16 + l15;
        int cg = col0 + cl;
        float tot = red[0][cl][0] + red[1][cl][0];
        float tsq = red[0][cl][1] + red[1][cl][1];
        float mu  = tot * (1.f / 128.f);
        float var = tsq * (1.f / 128.f) - mu * mu;
        float rv  = rsqrtf(var + BN_EPS);
        float g   = gamma[cg] * rv;
        float bt  = beta[cg] - mu * g;
#pragma unroll
        for (int m = 0; m < 4; ++m) {
#pragma unroll
            for (int r = 0; r < 4; ++r) {
                int rg = row0 + wr * 64 + m * 16 + lq * 4 + r;
                size_t idx = (size_t)rg * F + cg;
                z[idx] = (acc[m][n][r] * g + bt) * prior[idx];
            }
        }
    }
}

// ---------------- sparsemax (Michelot fixed-point), one wave per row ----------------
__global__ __launch_bounds__(256, 4) void sparsemax_kernel(float* __restrict__ z, int B, int F)
{
    const int lane = threadIdx.x & 63;
    const int wid  = threadIdx.x >> 6;
    const int row  = blockIdx.x * 4 + wid;
    if (row >= B) return;
    float* rp = z + (size_t)row * F;

    float4 v[8];
    float s = 0.f;
#pragma unroll
    for (int j = 0; j < 8; ++j) {
        v[j] = reinterpret_cast<const float4*>(rp)[j * 64 + lane];
        s += v[j].x + v[j].y + v[j].z + v[j].w;
    }
#pragma unroll
    for (int o = 32; o; o >>= 1) s += __shfl_xor(s, o);

    float tau = (s - 1.f) / (float)F;
    int cprev = F;
    for (int it = 0; it < 64; ++it) {
        float s2 = 0.f; int c2 = 0;
#pragma unroll
        for (int j = 0; j < 8; ++j) {
            if (v[j].x > tau) { s2 += v[j].x; ++c2; }
            if (v[j].y > tau) { s2 += v[j].y; ++c2; }
            if (v[j].z > tau) { s2 += v[j].z; ++c2; }
            if (v[j].w > tau) { s2 += v[j].w; ++c2; }
        }
#pragma unroll
        for (int o = 32; o; o >>= 1) { s2 += __shfl_xor(s2, o); c2 += __shfl_xor(c2, o); }
        if (c2 == cprev) break;
        tau = (s2 - 1.f) / (float)c2;
        cprev = c2;
    }

#pragma unroll
    for (int j = 0; j < 8; ++j) {
        float4 o4;
        o4.x = fmaxf(v[j].x - tau, 0.f);
        o4.y = fmaxf(v[j].y - tau, 0.f);
        o4.z = fmaxf(v[j].z - tau, 0.f);
        o4.w = fmaxf(v[j].w - tau, 0.f);
        reinterpret_cast<float4*>(rp)[j * 64 + lane] = o4;
    }
}

extern "C" void kernel_launch(void* const* d_in, const int* in_sizes, int n_in,
                              void* d_out, int out_size, void* d_ws, size_t ws_size,
                              hipStream_t stream) {
    const float* x     = (const float*)d_in[0];
    const float* prior = (const float*)d_in[1];
    const float* W     = (const float*)d_in[2];
    const float* gamma = (const float*)d_in[3];
    const float* beta  = (const float*)d_in[4];
    float* out = (float*)d_out;

    const int F = in_sizes[3];              // 2048
    const int K = in_sizes[2] / F;          // 512
    const int B = in_sizes[0] / K;          // 16384

    const size_t nx = (size_t)B * K;
    const size_t nw = (size_t)F * K;
    const size_t need = (nx + nw) * sizeof(unsigned short);

    if (ws_size >= need) {
        unsigned short* xb = (unsigned short*)d_ws;
        unsigned short* Wb = xb + nx;
        int nx8 = (int)(nx / 8), nw8 = (int)(nw / 8);
        int tot8 = nx8 + nw8;
        cvt_bf16_kernel<<<dim3((tot8 + 255) / 256), dim3(256), 0, stream>>>(x, xb, nx8, W, Wb, nw8);
        dim3 g1(F / 128, B / 128);
        gemm_bn_db_kernel<<<g1, dim3(256), 0, stream>>>(xb, Wb, gamma, beta, prior, out, B, F, K);
    } else {
        dim3 g1(F / 128, B / 128);
        gemm_bn_kernel<<<g1, dim3(256), 0, stream>>>(x, W, gamma, beta, prior, out, B, F, K);
    }
    sparsemax_kernel<<<dim3(B / 4), dim3(256), 0, stream>>>(out, B, F);
}